// Round 5
// baseline (250.375 us; speedup 1.0000x reference)
//
#include <hip/hip_runtime.h>

// MI355X / gfx950. bf16 MFMA BERT attention with relu^2 "softmax".
// mfma_f32_16x16x32_bf16 layouts (HW-verified):
//   A: lane l holds A[m=l&15][k=(l>>4)*8+j]
//   B: lane l holds B[k=(l>>4)*8+j][n=l&15]
//   C/D: lane l reg r holds D[row=(l>>4)*4+r][col=l&15]
// mfma_f32_16x16x16_bf16 (K=16):
//   A: lane l holds A[m=l&15][k=(l>>4)*4+j]  <-- matches 16x16x32 C-layout
// R11b: identical to R11 (container infra failure, no kernel evidence).
// attn restructured to the qkv-style single-barrier pipeline with KVBLK=128
// processed as two 64-key halves (same per-half code/registers):
//   { stage(t+1): 4 glds; compute half0; compute half1; vmcnt(0); barrier }
// Barriers 64->16 per kernel; the vmcnt(0) drain sits AFTER ~2000 cycles of
// compute so the prefetch is fully hidden (R10's vmcnt(2) sat right before
// compute and exposed latency every 64-key tile). Race-free like qkv: buf
// (t+1)&1's last readers finished before barrier end-of-(t-1) < stage issue.
// LDS 72KB -> 2 blocks/CU (grid 512 = 2/CU). qkv/convert unchanged.

typedef __bf16 bf16x8 __attribute__((ext_vector_type(8)));
typedef __bf16 bf16x4 __attribute__((ext_vector_type(4)));
typedef short  s16x4  __attribute__((ext_vector_type(4)));
typedef float  f32x4  __attribute__((ext_vector_type(4)));
typedef float  floatx4 __attribute__((ext_vector_type(4)));

#define MFMA16(a, b, c) __builtin_amdgcn_mfma_f32_16x16x32_bf16(a, b, c, 0, 0, 0)
// K=16 bf16 MFMA (gfx90a+ builtin, instruction present on gfx950 per ISA)
#define MFMA16K16(a, b, c) \
    __builtin_amdgcn_mfma_f32_16x16x16bf16_1k(a, b, c, 0, 0, 0)

#define WAITCNT_VM0() __builtin_amdgcn_s_waitcnt(0x0F70)   // vmcnt(0)
#define BARRIER() __builtin_amdgcn_s_barrier()
#define SETPRIO(p) __builtin_amdgcn_s_setprio(p)

__device__ __forceinline__ void glds16(const __bf16* g, __bf16* l) {
    __builtin_amdgcn_global_load_lds(
        (const __attribute__((address_space(1))) void*)g,
        (__attribute__((address_space(3))) void*)l, 16, 0, 0);
}

// ---------------------------------------------------------------------------
// fp32 -> bf16 conversion: X (8M elems) then Wq/Wk/Wv (1M each).
// ---------------------------------------------------------------------------
__global__ __launch_bounds__(256) void convert_kernel(
    const float* __restrict__ X, const float* __restrict__ Wq,
    const float* __restrict__ Wk, const float* __restrict__ Wv,
    __bf16* __restrict__ Xb, __bf16* __restrict__ Wqb,
    __bf16* __restrict__ Wkb, __bf16* __restrict__ Wvb)
{
    int blk = blockIdx.x;
    const float* src; __bf16* dst; size_t base;
    if (blk < 4096)      { src = X;  dst = Xb;  base = (size_t)blk * 2048; }
    else if (blk < 4608) { src = Wq; dst = Wqb; base = (size_t)(blk - 4096) * 2048; }
    else if (blk < 5120) { src = Wk; dst = Wkb; base = (size_t)(blk - 4608) * 2048; }
    else                 { src = Wv; dst = Wvb; base = (size_t)(blk - 5120) * 2048; }
    size_t off = base + (size_t)threadIdx.x * 8;
    floatx4 a = *(const floatx4*)(src + off);
    floatx4 c = *(const floatx4*)(src + off + 4);
    bf16x8 o;
    o[0] = (__bf16)a[0]; o[1] = (__bf16)a[1]; o[2] = (__bf16)a[2]; o[3] = (__bf16)a[3];
    o[4] = (__bf16)c[0]; o[5] = (__bf16)c[1]; o[6] = (__bf16)c[2]; o[7] = (__bf16)c[3];
    *(bf16x8*)(dst + off) = o;
}

// ---------------------------------------------------------------------------
// Fused QKV GEMM: out = Xb @ Wb.T + bias. 128x128 tile, BK=64, double-
// buffered glds staging, ONE s_barrier per K-step (T3-minimal):
//   { stage(s+1 -> nb); frag-read + 32 MFMA on bc; vmcnt(0); barrier }
// Race-free: stage writes buf (s+1)&1 while all waves read s&1; buf s&1 is
// only overwritten at iter s+2's stage, after barrier(s+1).
// blockIdx.x: 0-7 -> Q, 8-15 -> K, 16-23 -> V(transposed).
// ---------------------------------------------------------------------------
__global__ __launch_bounds__(256) void qkv_gemm_kernel(
    const __bf16* __restrict__ Xb,
    const __bf16* __restrict__ Wqb, const __bf16* __restrict__ Wkb,
    const __bf16* __restrict__ Wvb,
    const float* __restrict__ bq, const float* __restrict__ bk,
    const float* __restrict__ bv,
    __bf16* __restrict__ qws, __bf16* __restrict__ kws, __bf16* __restrict__ vws)
{
    __shared__ __bf16 As[2][128 * 64];
    __shared__ __bf16 Bs[2][128 * 64];

    const int tid  = threadIdx.x;
    const int lane = tid & 63;
    const int wave = tid >> 6;
    const int wm   = (wave >> 1) * 64;
    const int wn   = (wave & 1) * 64;
    const int quad = lane >> 4;
    const int l16  = lane & 15;
    const int m0   = blockIdx.y * 128;

    const int sel = blockIdx.x >> 3;
    const bool vmode = (sel == 2);
    const __bf16* Wb = (sel == 0) ? Wqb : (sel == 1) ? Wkb : Wvb;
    const float* bias = (sel == 0) ? bq : (sel == 1) ? bk : bv;
    __bf16* outp = (sel == 0) ? qws : (sel == 1) ? kws : vws;
    const int n0 = (blockIdx.x & 7) * 128;

    const int woffA = vmode ? wm : wn;
    const int woffB = vmode ? wn : wm;

    // staging lane geometry: one glds fills 8 rows x 64 cols (1KB).
    const int srow = lane >> 3;              // row within 8-row block
    const int schk = lane & 7;               // 16B chunk this lane fills

    f32x4 acc[4][4] = {};

    // ---- prologue: stage k-step 0 into buffer 0 (8 glds/wave) ----
    #pragma unroll
    for (int i = 0; i < 4; ++i) {
        int rb = wave * 32 + i * 8;
        int r  = rb + srow;
        int c  = schk ^ (r & 7);
        glds16(Xb + (size_t)(m0 + r) * 1024 + c * 8, &As[0][rb * 64]);
        glds16(Wb + (size_t)(n0 + r) * 1024 + c * 8, &Bs[0][rb * 64]);
    }
    WAITCNT_VM0();
    BARRIER();

    for (int s = 0; s < 16; ++s) {
        const int kn = ((s + 1) & 15) * 64;   // wrap: final restage benign
        const int nb = (s + 1) & 1;
        const int bc = s & 1;
        // ---- stage next k-step (8 glds/wave) ----
        #pragma unroll
        for (int i = 0; i < 4; ++i) {
            int rb = wave * 32 + i * 8;
            int r  = rb + srow;
            int c  = schk ^ (r & 7);
            glds16(Xb + (size_t)(m0 + r) * 1024 + kn + c * 8, &As[nb][rb * 64]);
            glds16(Wb + (size_t)(n0 + r) * 1024 + kn + c * 8, &Bs[nb][rb * 64]);
        }

        const __bf16* Pa_ = vmode ? &As[bc][0] : &Bs[bc][0];
        const __bf16* Pb_ = vmode ? &Bs[bc][0] : &As[bc][0];

        SETPRIO(1);
        #pragma unroll
        for (int kk8 = 0; kk8 < 8; kk8 += 4) {
            bf16x8 af[4], bfr[4];
            #pragma unroll
            for (int a = 0; a < 4; ++a)
                af[a] = *(const bf16x8*)&Pa_[(woffA + a * 16 + l16) * 64 +
                                             (((kk8 + quad) ^ (l16 & 7)) * 8)];
            #pragma unroll
            for (int bb = 0; bb < 4; ++bb)
                bfr[bb] = *(const bf16x8*)&Pb_[(woffB + bb * 16 + l16) * 64 +
                                               (((kk8 + quad) ^ (l16 & 7)) * 8)];
            #pragma unroll
            for (int a = 0; a < 4; ++a)
                #pragma unroll
                for (int bb = 0; bb < 4; ++bb)
                    acc[a][bb] = MFMA16(af[a], bfr[bb], acc[a][bb]);
        }
        SETPRIO(0);

        WAITCNT_VM0();          // this iter's stage (issued ~full compute ago)
        BARRIER();              // buf nb fully written before anyone reads it
    }

    if (!vmode) {
        #pragma unroll
        for (int a = 0; a < 4; ++a) {
            int n = n0 + woffA + a * 16 + quad * 4;
            floatx4 bv4 = *(const floatx4*)&bias[n];
            int h = n >> 6, d0 = n & 63;
            #pragma unroll
            for (int bb = 0; bb < 4; ++bb) {
                int m = m0 + woffB + bb * 16 + l16;
                int bt = m >> 11, ss = m & 2047;
                bf16x4 o;
                #pragma unroll
                for (int r = 0; r < 4; ++r)
                    o[r] = (__bf16)(acc[a][bb][r] + bv4[r]);
                *(bf16x4*)&outp[((size_t)(bt * 16 + h) * 2048 + ss) * 64 + d0] = o;
            }
        }
    } else {
        #pragma unroll
        for (int a = 0; a < 4; ++a) {
            int m = m0 + woffA + a * 16 + quad * 4;
            int bt = m >> 11, s0 = m & 2047;
            #pragma unroll
            for (int bb = 0; bb < 4; ++bb) {
                int n = n0 + woffB + bb * 16 + l16;
                float bvv = bias[n];
                int h = n >> 6, d = n & 63;
                bf16x4 o;
                #pragma unroll
                for (int r = 0; r < 4; ++r)
                    o[r] = (__bf16)(acc[a][bb][r] + bvv);
                *(bf16x4*)&outp[((size_t)(bt * 16 + h) * 64 + d) * 2048 + s0] = o;
            }
        }
    }
}

// ---------------------------------------------------------------------------
// Attention R11: grid (64, 8) -- blockIdx.x = head (bh) -> XCD = bh%8 keeps
// each head's K/V on one L2 (R10 win: FETCH 143MB -> 30MB). 8 waves/block,
// 32 q-rows/wave; mask row in LDS. KVBLK=128 as two 64-key halves over
// double-buffered sub-tiles; ONE barrier per 128 keys, stage-first:
//   { stage(t+1): 4 glds; compute h0; compute h1; vmcnt(0); barrier }
// ---------------------------------------------------------------------------
__global__ __launch_bounds__(512, 4) void attn_kernel(
    const __bf16* __restrict__ Q, const __bf16* __restrict__ K,
    const __bf16* __restrict__ Vt, const float* __restrict__ mask,
    float* __restrict__ out)
{
    __shared__ __bf16 Ks[2][2][64 * 64];   // [buf][half][key][d], swizzled
    __shared__ __bf16 Vs[2][2][64 * 64];   // [buf][half][d][key], swizzled
    __shared__ float  Ms[2048];            // full mask row for this batch

    const int tid  = threadIdx.x;
    const int lane = tid & 63;
    const int wave = tid >> 6;          // 0..7
    const int quad = lane >> 4;
    const int l16  = lane & 15;
    const int bh   = blockIdx.x;        // head index -> XCD = bh % 8
    const int b    = bh >> 4;
    const int h    = bh & 15;
    const int q0   = blockIdx.y * 256 + wave * 32;

    const __bf16* Qb = Q  + (size_t)bh * 2048 * 64;
    const __bf16* Kb = K  + (size_t)bh * 2048 * 64;
    const __bf16* Vb = Vt + (size_t)bh * 64 * 2048;
    const float*  mb = mask + b * 2048;

    // staging lane geometry: per glds a wave fills 8 rows x 64 cols (1KB).
    const int rb = wave * 8;                       // LDS row base this wave
    const int sr = rb + (lane >> 3);               // row this lane reads
    const int sc = ((lane & 7) ^ (sr & 7)) * 8;    // swizzled elem offset

    // Q fragments (B operand for S^T): lane n=l16 -> q, k = 8 contiguous d.
    bf16x8 aq[2][2];
    #pragma unroll
    for (int qi = 0; qi < 2; ++qi)
        #pragma unroll
        for (int kcd = 0; kcd < 2; ++kcd)
            aq[qi][kcd] = *(const bf16x8*)(Qb +
                (size_t)(q0 + qi * 16 + l16) * 64 + kcd * 32 + quad * 8);

    f32x4 co[2][4] = {};   // ctx[q-tile][d-tile], rows=q, cols=d

    // ---- prologue: stage tile 0 (4 glds/wave) + mask row (1 glds/wave) ----
    glds16(Kb + (size_t)sr * 64 + sc,        &Ks[0][0][rb * 64]);
    glds16(Kb + (size_t)(64 + sr) * 64 + sc, &Ks[0][1][rb * 64]);
    glds16(Vb + (size_t)sr * 2048 + sc,      &Vs[0][0][rb * 64]);
    glds16(Vb + (size_t)sr * 2048 + 64 + sc, &Vs[0][1][rb * 64]);
    // wave w stages mask floats [w*256, w*256+256): 64 lanes x 16B = 1KB
    glds16((const __bf16*)mb + (size_t)wave * 512 + lane * 8,
           (__bf16*)Ms + wave * 512);
    WAITCNT_VM0();
    BARRIER();

    for (int t = 0; t < 16; ++t) {
        const int kn = ((t + 1) & 15) * 128;  // wrap: final restage benign
        const int nb = (t + 1) & 1;
        const int cb = t & 1;
        // ---- stage next 128-key tile (4 glds/wave) ----
        glds16(Kb + (size_t)(kn + sr) * 64 + sc,       &Ks[nb][0][rb * 64]);
        glds16(Kb + (size_t)(kn + 64 + sr) * 64 + sc,  &Ks[nb][1][rb * 64]);
        glds16(Vb + (size_t)sr * 2048 + kn + sc,       &Vs[nb][0][rb * 64]);
        glds16(Vb + (size_t)sr * 2048 + kn + 64 + sc,  &Vs[nb][1][rb * 64]);

        #pragma unroll
        for (int hf = 0; hf < 2; ++hf) {
            const __bf16* Kt = &Ks[cb][hf][0];
            const __bf16* Vtile = &Vs[cb][hf][0];
            const int k0 = t * 128 + hf * 64;

            // ---- phase 1: all S^T MFMAs (K Q^T) ----
            f32x4 st[4][2] = {};                       // [ki][qi]
            SETPRIO(1);
            #pragma unroll
            for (int ki = 0; ki < 4; ++ki) {
                #pragma unroll
                for (int kcd = 0; kcd < 2; ++kcd) {
                    int key = ki * 16 + l16;
                    bf16x8 ak = *(const bf16x8*)&Kt[key * 64 +
                        (((kcd * 4 + quad) ^ (key & 7)) * 8)];
                    #pragma unroll
                    for (int qi = 0; qi < 2; ++qi)
                        st[ki][qi] = MFMA16(ak, aq[qi][kcd], st[ki][qi]);
                }
            }
            SETPRIO(0);

            // ---- phase 2: relu^2 pack into PV A-frags (vector f32 math) --
            bf16x4 pf[4][2];                           // [ki][qi]
            const f32x4 zero4 = {};
            #pragma unroll
            for (int ki = 0; ki < 4; ++ki) {
                f32x4 mk = *(const f32x4*)&Ms[k0 + ki * 16 + quad * 4];
                #pragma unroll
                for (int qi = 0; qi < 2; ++qi) {
                    f32x4 x = st[ki][qi] * 0.125f + mk;      // v_pk_fma_f32
                    x = __builtin_elementwise_max(x, zero4); // v_pk_max_f32
                    x = x * x;                               // v_pk_mul_f32
                    bf16x4 pv;
                    pv[0] = (__bf16)x[0]; pv[1] = (__bf16)x[1];
                    pv[2] = (__bf16)x[2]; pv[3] = (__bf16)x[3];
                    pf[ki][qi] = pv;
                }
            }

            // ---- phase 3: PV: ctx[q][d] += P V via 16x16x16 (A in regs) --
            SETPRIO(1);
            #pragma unroll
            for (int ki = 0; ki < 4; ++ki) {
                bf16x4 vb4[4];
                #pragma unroll
                for (int dt = 0; dt < 4; ++dt) {
                    int d = dt * 16 + l16;
                    int g = ki * 2 + (quad >> 1);       // global 8-elem chunk
                    vb4[dt] = *(const bf16x4*)&Vtile[d * 64 +
                        ((g ^ (d & 7)) * 8) + (quad & 1) * 4];
                }
                #pragma unroll
                for (int qi = 0; qi < 2; ++qi) {
                    s16x4 pa = __builtin_bit_cast(s16x4, pf[ki][qi]);
                    #pragma unroll
                    for (int dt = 0; dt < 4; ++dt)
                        co[qi][dt] = MFMA16K16(pa,
                            __builtin_bit_cast(s16x4, vb4[dt]), co[qi][dt]);
                }
            }
            SETPRIO(0);
        }

        WAITCNT_VM0();          // this iter's stage (issued ~2000 cyc ago)
        BARRIER();              // buf nb fully written before anyone reads it
    }

    // Epilogue: ctx row = q = qi*16+quad*4+r, col = d = dt*16+l16.
    #pragma unroll
    for (int qi = 0; qi < 2; ++qi)
        #pragma unroll
        for (int r = 0; r < 4; ++r) {
            int q = q0 + qi * 16 + quad * 4 + r;
            float* orow = &out[(((size_t)b * 2048 + q) * 16 + h) * 64];
            #pragma unroll
            for (int dt = 0; dt < 4; ++dt)
                orow[dt * 16 + l16] = co[qi][dt][r];
        }
}

// ---------------------------------------------------------------------------
extern "C" void kernel_launch(void* const* d_in, const int* in_sizes, int n_in,
                              void* d_out, int out_size, void* d_ws, size_t ws_size,
                              hipStream_t stream) {
    const float* hidden = (const float*)d_in[0];   // [4,2048,1024]
    const float* mask   = (const float*)d_in[1];   // [4,1,1,2048]
    const float* Wq     = (const float*)d_in[2];
    const float* bq     = (const float*)d_in[3];
    const float* Wk     = (const float*)d_in[4];
    const float* bk     = (const float*)d_in[5];
    const float* Wv     = (const float*)d_in[6];
    const float* bv     = (const float*)d_in[7];
    float* out = (float*)d_out;

    __bf16* qws = (__bf16*)d_ws;                       // [64][2048][64]
    __bf16* kws = qws + (size_t)64 * 2048 * 64;        // [64][2048][64]
    __bf16* vws = kws + (size_t)64 * 2048 * 64;        // [64][64][2048]
    __bf16* Xb  = vws + (size_t)64 * 2048 * 64;        // [8192][1024]
    __bf16* Wqb = Xb  + (size_t)8192 * 1024;
    __bf16* Wkb = Wqb + (size_t)1024 * 1024;
    __bf16* Wvb = Wkb + (size_t)1024 * 1024;

    convert_kernel<<<dim3(5632), dim3(256), 0, stream>>>(hidden, Wq, Wk, Wv,
                                                         Xb, Wqb, Wkb, Wvb);
    qkv_gemm_kernel<<<dim3(24, 64), dim3(256), 0, stream>>>(Xb, Wqb, Wkb, Wvb,
                                                            bq, bk, bv,
                                                            qws, kws, vws);
    attn_kernel<<<dim3(64, 8), dim3(512), 0, stream>>>(qws, kws, vws, mask, out);
}

// Round 6
// 241.327 us; speedup vs baseline: 1.0375x; 1.0375x over previous
//
#include <hip/hip_runtime.h>

// MI355X / gfx950. bf16 MFMA BERT attention with relu^2 "softmax".
// R12: attn compute moved to FULL-RATE 32x32x16 MFMAs for both S^T and PV.
// R11's PV used 16x16x16 (K=16) = half-rate: 32 of 48 MFMA slots per half
// were half-FLOP. New scheme per 64-key half: S^T = 8x 32x32x16 (A=K-tile,
// B=Q^T), pack relu^2 in-register, repack to PV A-frags with 4
// v_permlane32_swap per 32-key group (lane l<->l+32 word exchange), PV =
// 8x 32x32x16 (A=P, B=V^T-slice). Matrix-pipe work -33%.
// 32x32 layouts (HW-verified C/D; A/B by the lane-mapping convention):
//   A: lane l holds A[m=l&31][k=(l>>5)*8+j]
//   B: lane l holds B[k=(l>>5)*8+j][n=l&31]
//   C/D: lane l reg r holds D[row=(r&3)+8*(r>>2)+4*(l>>5)][col=l&31]
// Pipeline unchanged from R11: { stage(t+1) 4 glds; compute h0; h1;
// vmcnt(0); barrier }, 16 barriers, grid (64,8) XCD-local K/V.
// qkv/convert unchanged.

typedef __bf16 bf16x8 __attribute__((ext_vector_type(8)));
typedef __bf16 bf16x4 __attribute__((ext_vector_type(4)));
typedef __bf16 bf16x2 __attribute__((ext_vector_type(2)));
typedef short  s16x4  __attribute__((ext_vector_type(4)));
typedef float  f32x4  __attribute__((ext_vector_type(4)));
typedef float  f32x16 __attribute__((ext_vector_type(16)));
typedef float  floatx4 __attribute__((ext_vector_type(4)));
typedef unsigned u32x2 __attribute__((ext_vector_type(2)));
typedef unsigned u32x4 __attribute__((ext_vector_type(4)));

#define MFMA16(a, b, c) __builtin_amdgcn_mfma_f32_16x16x32_bf16(a, b, c, 0, 0, 0)
#define MFMA32(a, b, c) __builtin_amdgcn_mfma_f32_32x32x16_bf16(a, b, c, 0, 0, 0)

#define WAITCNT_VM0() __builtin_amdgcn_s_waitcnt(0x0F70)   // vmcnt(0)
#define BARRIER() __builtin_amdgcn_s_barrier()
#define SETPRIO(p) __builtin_amdgcn_s_setprio(p)

__device__ __forceinline__ void glds16(const __bf16* g, __bf16* l) {
    __builtin_amdgcn_global_load_lds(
        (const __attribute__((address_space(1))) void*)g,
        (__attribute__((address_space(3))) void*)l, 16, 0, 0);
}

// ---------------------------------------------------------------------------
// fp32 -> bf16 conversion: X (8M elems) then Wq/Wk/Wv (1M each).
// ---------------------------------------------------------------------------
__global__ __launch_bounds__(256) void convert_kernel(
    const float* __restrict__ X, const float* __restrict__ Wq,
    const float* __restrict__ Wk, const float* __restrict__ Wv,
    __bf16* __restrict__ Xb, __bf16* __restrict__ Wqb,
    __bf16* __restrict__ Wkb, __bf16* __restrict__ Wvb)
{
    int blk = blockIdx.x;
    const float* src; __bf16* dst; size_t base;
    if (blk < 4096)      { src = X;  dst = Xb;  base = (size_t)blk * 2048; }
    else if (blk < 4608) { src = Wq; dst = Wqb; base = (size_t)(blk - 4096) * 2048; }
    else if (blk < 5120) { src = Wk; dst = Wkb; base = (size_t)(blk - 4608) * 2048; }
    else                 { src = Wv; dst = Wvb; base = (size_t)(blk - 5120) * 2048; }
    size_t off = base + (size_t)threadIdx.x * 8;
    floatx4 a = *(const floatx4*)(src + off);
    floatx4 c = *(const floatx4*)(src + off + 4);
    bf16x8 o;
    o[0] = (__bf16)a[0]; o[1] = (__bf16)a[1]; o[2] = (__bf16)a[2]; o[3] = (__bf16)a[3];
    o[4] = (__bf16)c[0]; o[5] = (__bf16)c[1]; o[6] = (__bf16)c[2]; o[7] = (__bf16)c[3];
    *(bf16x8*)(dst + off) = o;
}

// ---------------------------------------------------------------------------
// Fused QKV GEMM: out = Xb @ Wb.T + bias. 128x128 tile, BK=64, double-
// buffered glds staging, ONE s_barrier per K-step (T3-minimal):
//   { stage(s+1 -> nb); frag-read + 32 MFMA on bc; vmcnt(0); barrier }
// blockIdx.x: 0-7 -> Q, 8-15 -> K, 16-23 -> V(transposed).
// ---------------------------------------------------------------------------
__global__ __launch_bounds__(256) void qkv_gemm_kernel(
    const __bf16* __restrict__ Xb,
    const __bf16* __restrict__ Wqb, const __bf16* __restrict__ Wkb,
    const __bf16* __restrict__ Wvb,
    const float* __restrict__ bq, const float* __restrict__ bk,
    const float* __restrict__ bv,
    __bf16* __restrict__ qws, __bf16* __restrict__ kws, __bf16* __restrict__ vws)
{
    __shared__ __bf16 As[2][128 * 64];
    __shared__ __bf16 Bs[2][128 * 64];

    const int tid  = threadIdx.x;
    const int lane = tid & 63;
    const int wave = tid >> 6;
    const int wm   = (wave >> 1) * 64;
    const int wn   = (wave & 1) * 64;
    const int quad = lane >> 4;
    const int l16  = lane & 15;
    const int m0   = blockIdx.y * 128;

    const int sel = blockIdx.x >> 3;
    const bool vmode = (sel == 2);
    const __bf16* Wb = (sel == 0) ? Wqb : (sel == 1) ? Wkb : Wvb;
    const float* bias = (sel == 0) ? bq : (sel == 1) ? bk : bv;
    __bf16* outp = (sel == 0) ? qws : (sel == 1) ? kws : vws;
    const int n0 = (blockIdx.x & 7) * 128;

    const int woffA = vmode ? wm : wn;
    const int woffB = vmode ? wn : wm;

    const int srow = lane >> 3;              // row within 8-row block
    const int schk = lane & 7;               // 16B chunk this lane fills

    f32x4 acc[4][4] = {};

    #pragma unroll
    for (int i = 0; i < 4; ++i) {
        int rb = wave * 32 + i * 8;
        int r  = rb + srow;
        int c  = schk ^ (r & 7);
        glds16(Xb + (size_t)(m0 + r) * 1024 + c * 8, &As[0][rb * 64]);
        glds16(Wb + (size_t)(n0 + r) * 1024 + c * 8, &Bs[0][rb * 64]);
    }
    WAITCNT_VM0();
    BARRIER();

    for (int s = 0; s < 16; ++s) {
        const int kn = ((s + 1) & 15) * 64;   // wrap: final restage benign
        const int nb = (s + 1) & 1;
        const int bc = s & 1;
        #pragma unroll
        for (int i = 0; i < 4; ++i) {
            int rb = wave * 32 + i * 8;
            int r  = rb + srow;
            int c  = schk ^ (r & 7);
            glds16(Xb + (size_t)(m0 + r) * 1024 + kn + c * 8, &As[nb][rb * 64]);
            glds16(Wb + (size_t)(n0 + r) * 1024 + kn + c * 8, &Bs[nb][rb * 64]);
        }

        const __bf16* Pa_ = vmode ? &As[bc][0] : &Bs[bc][0];
        const __bf16* Pb_ = vmode ? &Bs[bc][0] : &As[bc][0];

        SETPRIO(1);
        #pragma unroll
        for (int kk8 = 0; kk8 < 8; kk8 += 4) {
            bf16x8 af[4], bfr[4];
            #pragma unroll
            for (int a = 0; a < 4; ++a)
                af[a] = *(const bf16x8*)&Pa_[(woffA + a * 16 + l16) * 64 +
                                             (((kk8 + quad) ^ (l16 & 7)) * 8)];
            #pragma unroll
            for (int bb = 0; bb < 4; ++bb)
                bfr[bb] = *(const bf16x8*)&Pb_[(woffB + bb * 16 + l16) * 64 +
                                               (((kk8 + quad) ^ (l16 & 7)) * 8)];
            #pragma unroll
            for (int a = 0; a < 4; ++a)
                #pragma unroll
                for (int bb = 0; bb < 4; ++bb)
                    acc[a][bb] = MFMA16(af[a], bfr[bb], acc[a][bb]);
        }
        SETPRIO(0);

        WAITCNT_VM0();
        BARRIER();
    }

    if (!vmode) {
        #pragma unroll
        for (int a = 0; a < 4; ++a) {
            int n = n0 + woffA + a * 16 + quad * 4;
            floatx4 bv4 = *(const floatx4*)&bias[n];
            int h = n >> 6, d0 = n & 63;
            #pragma unroll
            for (int bb = 0; bb < 4; ++bb) {
                int m = m0 + woffB + bb * 16 + l16;
                int bt = m >> 11, ss = m & 2047;
                bf16x4 o;
                #pragma unroll
                for (int r = 0; r < 4; ++r)
                    o[r] = (__bf16)(acc[a][bb][r] + bv4[r]);
                *(bf16x4*)&outp[((size_t)(bt * 16 + h) * 2048 + ss) * 64 + d0] = o;
            }
        }
    } else {
        #pragma unroll
        for (int a = 0; a < 4; ++a) {
            int m = m0 + woffA + a * 16 + quad * 4;
            int bt = m >> 11, s0 = m & 2047;
            #pragma unroll
            for (int bb = 0; bb < 4; ++bb) {
                int n = n0 + woffB + bb * 16 + l16;
                float bvv = bias[n];
                int h = n >> 6, d = n & 63;
                bf16x4 o;
                #pragma unroll
                for (int r = 0; r < 4; ++r)
                    o[r] = (__bf16)(acc[a][bb][r] + bvv);
                *(bf16x4*)&outp[((size_t)(bt * 16 + h) * 64 + d) * 2048 + s0] = o;
            }
        }
    }
}

// ---------------------------------------------------------------------------
// Attention R12: grid (64, 8); 8 waves x 32 q-rows. KVBLK=128 as two 64-key
// halves; one barrier per tile. Per half:
//  S^T (2 kg x 4 dk 32x32x16, A=K from LDS, B=Q regs) ->
//  relu^2 pack (f32 vector) -> cvt bf16 -> 4 permlane32_swap per kg ->
//  PV (2 kg x 2 g16 x 2 dt 32x32x16, A=P regs, B=V from LDS).
// ---------------------------------------------------------------------------
__global__ __launch_bounds__(512, 4) void attn_kernel(
    const __bf16* __restrict__ Q, const __bf16* __restrict__ K,
    const __bf16* __restrict__ Vt, const float* __restrict__ mask,
    float* __restrict__ out)
{
    __shared__ __bf16 Ks[2][2][64 * 64];   // [buf][half][key][d], swizzled
    __shared__ __bf16 Vs[2][2][64 * 64];   // [buf][half][d][key], swizzled
    __shared__ float  Ms[2048];            // full mask row for this batch

    const int tid  = threadIdx.x;
    const int lane = tid & 63;
    const int wave = tid >> 6;          // 0..7
    const int l32  = lane & 31;
    const int hi   = lane >> 5;         // 0/1
    const int bh   = blockIdx.x;        // head index -> XCD = bh % 8
    const int b    = bh >> 4;
    const int h    = bh & 15;
    const int q0w  = blockIdx.y * 256 + wave * 32;

    const __bf16* Qb = Q  + (size_t)bh * 2048 * 64;
    const __bf16* Kb = K  + (size_t)bh * 2048 * 64;
    const __bf16* Vb = Vt + (size_t)bh * 64 * 2048;
    const float*  mb = mask + b * 2048;

    // staging lane geometry: per glds a wave fills 8 rows x 64 cols (1KB).
    const int rb = wave * 8;                       // LDS row base this wave
    const int sr = rb + (lane >> 3);               // row this lane reads
    const int sc = ((lane & 7) ^ (sr & 7)) * 8;    // swizzled elem offset

    // Q fragments (B operand of S^T): lane holds Q[q=q0w+l32][d=dk*16+hi*8+j]
    bf16x8 aq[4];
    #pragma unroll
    for (int dk = 0; dk < 4; ++dk)
        aq[dk] = *(const bf16x8*)(Qb +
            (size_t)(q0w + l32) * 64 + dk * 16 + hi * 8);

    f32x16 co0 = {}, co1 = {};   // ctx: rows=q (C layout), cols=d (dt*32+l32)

    // ---- prologue: stage tile 0 (4 glds/wave) + mask row (1 glds/wave) ----
    glds16(Kb + (size_t)sr * 64 + sc,        &Ks[0][0][rb * 64]);
    glds16(Kb + (size_t)(64 + sr) * 64 + sc, &Ks[0][1][rb * 64]);
    glds16(Vb + (size_t)sr * 2048 + sc,      &Vs[0][0][rb * 64]);
    glds16(Vb + (size_t)sr * 2048 + 64 + sc, &Vs[0][1][rb * 64]);
    glds16((const __bf16*)mb + (size_t)wave * 512 + lane * 8,
           (__bf16*)Ms + wave * 512);
    WAITCNT_VM0();
    BARRIER();

    for (int t = 0; t < 16; ++t) {
        const int kn = ((t + 1) & 15) * 128;  // wrap: final restage benign
        const int nb = (t + 1) & 1;
        const int cb = t & 1;
        // ---- stage next 128-key tile (4 glds/wave) ----
        glds16(Kb + (size_t)(kn + sr) * 64 + sc,       &Ks[nb][0][rb * 64]);
        glds16(Kb + (size_t)(kn + 64 + sr) * 64 + sc,  &Ks[nb][1][rb * 64]);
        glds16(Vb + (size_t)sr * 2048 + kn + sc,       &Vs[nb][0][rb * 64]);
        glds16(Vb + (size_t)sr * 2048 + kn + 64 + sc,  &Vs[nb][1][rb * 64]);

        #pragma unroll
        for (int hf = 0; hf < 2; ++hf) {
            const __bf16* Kt = &Ks[cb][hf][0];
            const __bf16* Vtl = &Vs[cb][hf][0];
            const int k0 = t * 128 + hf * 64;

            // ---- phase 1: S^T = K Q^T, two 32-key groups, K=16 chain ----
            f32x16 st0 = {}, st1 = {};
            SETPRIO(1);
            #pragma unroll
            for (int dk = 0; dk < 4; ++dk) {
                const int g = dk * 2 + hi;             // global d-chunk
                const int c0 = (g ^ (l32 & 7)) * 8;    // swizzled (row&7 dep)
                bf16x8 ak0 = *(const bf16x8*)&Kt[l32 * 64 + c0];
                bf16x8 ak1 = *(const bf16x8*)&Kt[(32 + l32) * 64 + c0];
                st0 = MFMA32(ak0, aq[dk], st0);
                st1 = MFMA32(ak1, aq[dk], st1);
            }
            SETPRIO(0);

            // ---- phase 2+3 per 32-key group ----
            #pragma unroll
            for (int kg = 0; kg < 2; ++kg) {
                const f32x16 s = kg ? st1 : st0;
                const f32x4 zero4 = {};
                unsigned W[4][2];
                #pragma unroll
                for (int G = 0; G < 4; ++G) {
                    f32x4 v;
                    v[0] = s[G * 4 + 0]; v[1] = s[G * 4 + 1];
                    v[2] = s[G * 4 + 2]; v[3] = s[G * 4 + 3];
                    f32x4 mk = *(const f32x4*)&Ms[k0 + kg * 32 + G * 8 + hi * 4];
                    v = v * 0.125f + mk;                      // v_pk_fma_f32
                    v = __builtin_elementwise_max(v, zero4);  // v_pk_max_f32
                    v = v * v;                                // v_pk_mul_f32
                    bf16x2 w0, w1;
                    w0[0] = (__bf16)v[0]; w0[1] = (__bf16)v[1];
                    w1[0] = (__bf16)v[2]; w1[1] = (__bf16)v[3];
                    W[G][0] = __builtin_bit_cast(unsigned, w0);
                    W[G][1] = __builtin_bit_cast(unsigned, w1);
                }
                // repack to K=16 A-frags: lane l<->l+32 word exchange.
                // swap(a,b): a' = {a_lo, b_lo}, b' = {a_hi, b_hi}
                u32x2 s00 = __builtin_amdgcn_permlane32_swap(W[0][0], W[1][0], false, false);
                u32x2 s01 = __builtin_amdgcn_permlane32_swap(W[0][1], W[1][1], false, false);
                u32x2 s10 = __builtin_amdgcn_permlane32_swap(W[2][0], W[3][0], false, false);
                u32x2 s11 = __builtin_amdgcn_permlane32_swap(W[2][1], W[3][1], false, false);
                u32x4 f0, f1;
                f0[0] = s00[0]; f0[1] = s01[0]; f0[2] = s00[1]; f0[3] = s01[1];
                f1[0] = s10[0]; f1[1] = s11[0]; f1[2] = s10[1]; f1[3] = s11[1];
                bf16x8 pa0 = __builtin_bit_cast(bf16x8, f0);   // keys kg*32+ 0..15
                bf16x8 pa1 = __builtin_bit_cast(bf16x8, f1);   // keys kg*32+16..31

                // ---- PV: co[dt] += P V, B = V^T slice from LDS ----
                SETPRIO(1);
                #pragma unroll
                for (int dt = 0; dt < 2; ++dt) {
                    const int d = dt * 32 + l32;
                    const int ch0 = (kg * 4 + hi) ^ (d & 7);
                    const int ch1 = (kg * 4 + 2 + hi) ^ (d & 7);
                    bf16x8 vb0 = *(const bf16x8*)&Vtl[d * 64 + ch0 * 8];
                    bf16x8 vb1 = *(const bf16x8*)&Vtl[d * 64 + ch1 * 8];
                    if (dt == 0) {
                        co0 = MFMA32(pa0, vb0, co0);
                        co0 = MFMA32(pa1, vb1, co0);
                    } else {
                        co1 = MFMA32(pa0, vb0, co1);
                        co1 = MFMA32(pa1, vb1, co1);
                    }
                }
                SETPRIO(0);
            }
        }

        WAITCNT_VM0();          // this iter's stage (issued ~3000 cyc ago)
        BARRIER();              // buf nb fully written before anyone reads it
    }

    // Epilogue: q = q0w + (r&3)+8*(r>>2)+4*hi, d = dt*32 + l32.
    #pragma unroll
    for (int r = 0; r < 16; ++r) {
        int q = q0w + (r & 3) + 8 * (r >> 2) + 4 * hi;
        float* orow = &out[(((size_t)b * 2048 + q) * 16 + h) * 64];
        orow[l32]      = co0[r];
        orow[32 + l32] = co1[r];
    }
}

// ---------------------------------------------------------------------------
extern "C" void kernel_launch(void* const* d_in, const int* in_sizes, int n_in,
                              void* d_out, int out_size, void* d_ws, size_t ws_size,
                              hipStream_t stream) {
    const float* hidden = (const float*)d_in[0];   // [4,2048,1024]
    const float* mask   = (const float*)d_in[1];   // [4,1,1,2048]
    const float* Wq     = (const float*)d_in[2];
    const float* bq     = (const float*)d_in[3];
    const float* Wk     = (const float*)d_in[4];
    const float* bk     = (const float*)d_in[5];
    const float* Wv     = (const float*)d_in[6];
    const float* bv     = (const float*)d_in[7];
    float* out = (float*)d_out;

    __bf16* qws = (__bf16*)d_ws;                       // [64][2048][64]
    __bf16* kws = qws + (size_t)64 * 2048 * 64;        // [64][2048][64]
    __bf16* vws = kws + (size_t)64 * 2048 * 64;        // [64][64][2048]
    __bf16* Xb  = vws + (size_t)64 * 2048 * 64;        // [8192][1024]
    __bf16* Wqb = Xb  + (size_t)8192 * 1024;
    __bf16* Wkb = Wqb + (size_t)1024 * 1024;
    __bf16* Wvb = Wkb + (size_t)1024 * 1024;

    convert_kernel<<<dim3(5632), dim3(256), 0, stream>>>(hidden, Wq, Wk, Wv,
                                                         Xb, Wqb, Wkb, Wvb);
    qkv_gemm_kernel<<<dim3(24, 64), dim3(256), 0, stream>>>(Xb, Wqb, Wkb, Wvb,
                                                            bq, bk, bv,
                                                            qws, kws, vws);
    attn_kernel<<<dim3(64, 8), dim3(512), 0, stream>>>(qws, kws, vws, mask, out);
}

// Round 7
// 241.033 us; speedup vs baseline: 1.0388x; 1.0012x over previous
//
#include <hip/hip_runtime.h>

// MI355X / gfx950. bf16 MFMA BERT attention with relu^2 "softmax".
// R13: attn occupancy restructure. R12 held 72KB LDS -> 2 blocks/CU -> two
// 8-wave lockstep barrier groups (occ 34%). Now KVBLK=64, 4 waves/block
// (128 q-rows), grid (64,16): LDS = 2x(8K+8K) + 8K mask = 40KB -> EXACTLY
// 4 blocks/CU = 4 independent 4-wave barrier groups; one group's MFMA phase
// hides another's stage/pack. Per-wave compute identical to R12 (full-rate
// 32x32x16 for S^T and PV, permlane32_swap repack, f32x4 vector relu^2).
// Pipeline per iter: { stage(t+1) 4 glds; compute 64-key tile; vmcnt(0);
// barrier }, 32 iters. XCD mapping preserved: id%8 = bh%8.
// 32x32 layouts (HW-verified C/D):
//   A: lane l holds A[m=l&31][k=(l>>5)*8+j]
//   B: lane l holds B[k=(l>>5)*8+j][n=l&31]
//   C/D: lane l reg r holds D[row=(r&3)+8*(r>>2)+4*(l>>5)][col=l&31]
// qkv/convert unchanged.

typedef __bf16 bf16x8 __attribute__((ext_vector_type(8)));
typedef __bf16 bf16x4 __attribute__((ext_vector_type(4)));
typedef __bf16 bf16x2 __attribute__((ext_vector_type(2)));
typedef short  s16x4  __attribute__((ext_vector_type(4)));
typedef float  f32x4  __attribute__((ext_vector_type(4)));
typedef float  f32x16 __attribute__((ext_vector_type(16)));
typedef float  floatx4 __attribute__((ext_vector_type(4)));
typedef unsigned u32x2 __attribute__((ext_vector_type(2)));
typedef unsigned u32x4 __attribute__((ext_vector_type(4)));

#define MFMA16(a, b, c) __builtin_amdgcn_mfma_f32_16x16x32_bf16(a, b, c, 0, 0, 0)
#define MFMA32(a, b, c) __builtin_amdgcn_mfma_f32_32x32x16_bf16(a, b, c, 0, 0, 0)

#define WAITCNT_VM0() __builtin_amdgcn_s_waitcnt(0x0F70)   // vmcnt(0)
#define BARRIER() __builtin_amdgcn_s_barrier()
#define SETPRIO(p) __builtin_amdgcn_s_setprio(p)

__device__ __forceinline__ void glds16(const __bf16* g, __bf16* l) {
    __builtin_amdgcn_global_load_lds(
        (const __attribute__((address_space(1))) void*)g,
        (__attribute__((address_space(3))) void*)l, 16, 0, 0);
}

// ---------------------------------------------------------------------------
// fp32 -> bf16 conversion: X (8M elems) then Wq/Wk/Wv (1M each).
// ---------------------------------------------------------------------------
__global__ __launch_bounds__(256) void convert_kernel(
    const float* __restrict__ X, const float* __restrict__ Wq,
    const float* __restrict__ Wk, const float* __restrict__ Wv,
    __bf16* __restrict__ Xb, __bf16* __restrict__ Wqb,
    __bf16* __restrict__ Wkb, __bf16* __restrict__ Wvb)
{
    int blk = blockIdx.x;
    const float* src; __bf16* dst; size_t base;
    if (blk < 4096)      { src = X;  dst = Xb;  base = (size_t)blk * 2048; }
    else if (blk < 4608) { src = Wq; dst = Wqb; base = (size_t)(blk - 4096) * 2048; }
    else if (blk < 5120) { src = Wk; dst = Wkb; base = (size_t)(blk - 4608) * 2048; }
    else                 { src = Wv; dst = Wvb; base = (size_t)(blk - 5120) * 2048; }
    size_t off = base + (size_t)threadIdx.x * 8;
    floatx4 a = *(const floatx4*)(src + off);
    floatx4 c = *(const floatx4*)(src + off + 4);
    bf16x8 o;
    o[0] = (__bf16)a[0]; o[1] = (__bf16)a[1]; o[2] = (__bf16)a[2]; o[3] = (__bf16)a[3];
    o[4] = (__bf16)c[0]; o[5] = (__bf16)c[1]; o[6] = (__bf16)c[2]; o[7] = (__bf16)c[3];
    *(bf16x8*)(dst + off) = o;
}

// ---------------------------------------------------------------------------
// Fused QKV GEMM: out = Xb @ Wb.T + bias. 128x128 tile, BK=64, double-
// buffered glds staging, ONE s_barrier per K-step (T3-minimal):
//   { stage(s+1 -> nb); frag-read + 32 MFMA on bc; vmcnt(0); barrier }
// blockIdx.x: 0-7 -> Q, 8-15 -> K, 16-23 -> V(transposed).
// ---------------------------------------------------------------------------
__global__ __launch_bounds__(256) void qkv_gemm_kernel(
    const __bf16* __restrict__ Xb,
    const __bf16* __restrict__ Wqb, const __bf16* __restrict__ Wkb,
    const __bf16* __restrict__ Wvb,
    const float* __restrict__ bq, const float* __restrict__ bk,
    const float* __restrict__ bv,
    __bf16* __restrict__ qws, __bf16* __restrict__ kws, __bf16* __restrict__ vws)
{
    __shared__ __bf16 As[2][128 * 64];
    __shared__ __bf16 Bs[2][128 * 64];

    const int tid  = threadIdx.x;
    const int lane = tid & 63;
    const int wave = tid >> 6;
    const int wm   = (wave >> 1) * 64;
    const int wn   = (wave & 1) * 64;
    const int quad = lane >> 4;
    const int l16  = lane & 15;
    const int m0   = blockIdx.y * 128;

    const int sel = blockIdx.x >> 3;
    const bool vmode = (sel == 2);
    const __bf16* Wb = (sel == 0) ? Wqb : (sel == 1) ? Wkb : Wvb;
    const float* bias = (sel == 0) ? bq : (sel == 1) ? bk : bv;
    __bf16* outp = (sel == 0) ? qws : (sel == 1) ? kws : vws;
    const int n0 = (blockIdx.x & 7) * 128;

    const int woffA = vmode ? wm : wn;
    const int woffB = vmode ? wn : wm;

    const int srow = lane >> 3;              // row within 8-row block
    const int schk = lane & 7;               // 16B chunk this lane fills

    f32x4 acc[4][4] = {};

    #pragma unroll
    for (int i = 0; i < 4; ++i) {
        int rb = wave * 32 + i * 8;
        int r  = rb + srow;
        int c  = schk ^ (r & 7);
        glds16(Xb + (size_t)(m0 + r) * 1024 + c * 8, &As[0][rb * 64]);
        glds16(Wb + (size_t)(n0 + r) * 1024 + c * 8, &Bs[0][rb * 64]);
    }
    WAITCNT_VM0();
    BARRIER();

    for (int s = 0; s < 16; ++s) {
        const int kn = ((s + 1) & 15) * 64;   // wrap: final restage benign
        const int nb = (s + 1) & 1;
        const int bc = s & 1;
        #pragma unroll
        for (int i = 0; i < 4; ++i) {
            int rb = wave * 32 + i * 8;
            int r  = rb + srow;
            int c  = schk ^ (r & 7);
            glds16(Xb + (size_t)(m0 + r) * 1024 + kn + c * 8, &As[nb][rb * 64]);
            glds16(Wb + (size_t)(n0 + r) * 1024 + kn + c * 8, &Bs[nb][rb * 64]);
        }

        const __bf16* Pa_ = vmode ? &As[bc][0] : &Bs[bc][0];
        const __bf16* Pb_ = vmode ? &Bs[bc][0] : &As[bc][0];

        SETPRIO(1);
        #pragma unroll
        for (int kk8 = 0; kk8 < 8; kk8 += 4) {
            bf16x8 af[4], bfr[4];
            #pragma unroll
            for (int a = 0; a < 4; ++a)
                af[a] = *(const bf16x8*)&Pa_[(woffA + a * 16 + l16) * 64 +
                                             (((kk8 + quad) ^ (l16 & 7)) * 8)];
            #pragma unroll
            for (int bb = 0; bb < 4; ++bb)
                bfr[bb] = *(const bf16x8*)&Pb_[(woffB + bb * 16 + l16) * 64 +
                                               (((kk8 + quad) ^ (l16 & 7)) * 8)];
            #pragma unroll
            for (int a = 0; a < 4; ++a)
                #pragma unroll
                for (int bb = 0; bb < 4; ++bb)
                    acc[a][bb] = MFMA16(af[a], bfr[bb], acc[a][bb]);
        }
        SETPRIO(0);

        WAITCNT_VM0();
        BARRIER();
    }

    if (!vmode) {
        #pragma unroll
        for (int a = 0; a < 4; ++a) {
            int n = n0 + woffA + a * 16 + quad * 4;
            floatx4 bv4 = *(const floatx4*)&bias[n];
            int h = n >> 6, d0 = n & 63;
            #pragma unroll
            for (int bb = 0; bb < 4; ++bb) {
                int m = m0 + woffB + bb * 16 + l16;
                int bt = m >> 11, ss = m & 2047;
                bf16x4 o;
                #pragma unroll
                for (int r = 0; r < 4; ++r)
                    o[r] = (__bf16)(acc[a][bb][r] + bv4[r]);
                *(bf16x4*)&outp[((size_t)(bt * 16 + h) * 2048 + ss) * 64 + d0] = o;
            }
        }
    } else {
        #pragma unroll
        for (int a = 0; a < 4; ++a) {
            int m = m0 + woffA + a * 16 + quad * 4;
            int bt = m >> 11, s0 = m & 2047;
            #pragma unroll
            for (int bb = 0; bb < 4; ++bb) {
                int n = n0 + woffB + bb * 16 + l16;
                float bvv = bias[n];
                int h = n >> 6, d = n & 63;
                bf16x4 o;
                #pragma unroll
                for (int r = 0; r < 4; ++r)
                    o[r] = (__bf16)(acc[a][bb][r] + bvv);
                *(bf16x4*)&outp[((size_t)(bt * 16 + h) * 64 + d) * 2048 + s0] = o;
            }
        }
    }
}

// ---------------------------------------------------------------------------
// Attention R13: grid (64, 16); 4 waves x 32 q-rows = 128 q/block.
// LDS 40KB -> 4 blocks/CU (4 independent barrier groups). KVBLK=64, one
// barrier per tile: { stage(t+1) 4 glds; S^T; pack; PV; vmcnt(0); barrier }.
// Per-wave compute identical to R12's per-half body.
// ---------------------------------------------------------------------------
__global__ __launch_bounds__(256, 4) void attn_kernel(
    const __bf16* __restrict__ Q, const __bf16* __restrict__ K,
    const __bf16* __restrict__ Vt, const float* __restrict__ mask,
    float* __restrict__ out)
{
    __shared__ __bf16 Ks[2][64 * 64];   // [buf][key][d], swizzled chunks
    __shared__ __bf16 Vs[2][64 * 64];   // [buf][d][key], swizzled chunks
    __shared__ float  Ms[2048];         // full mask row for this batch

    const int tid  = threadIdx.x;
    const int lane = tid & 63;
    const int wave = tid >> 6;          // 0..3
    const int l32  = lane & 31;
    const int hi   = lane >> 5;         // 0/1
    const int bh   = blockIdx.x;        // head index -> XCD = bh % 8
    const int b    = bh >> 4;
    const int h    = bh & 15;
    const int q0w  = blockIdx.y * 128 + wave * 32;

    const __bf16* Qb = Q  + (size_t)bh * 2048 * 64;
    const __bf16* Kb = K  + (size_t)bh * 2048 * 64;
    const __bf16* Vb = Vt + (size_t)bh * 64 * 2048;
    const float*  mb = mask + b * 2048;

    // staging lane geometry: per glds a wave fills 8 rows x 64 cols (1KB);
    // each wave stages 16 rows of K and 16 rows of V (2 glds each).
    const int rb = wave * 16;                      // LDS row base this wave
    const int sr = rb + (lane >> 3);               // row (first 8-row block)
    const int sc = ((lane & 7) ^ (sr & 7)) * 8;    // swizzle: (sr+8)&7==sr&7

    // Q fragments (B operand of S^T): lane holds Q[q=q0w+l32][d=dk*16+hi*8+j]
    bf16x8 aq[4];
    #pragma unroll
    for (int dk = 0; dk < 4; ++dk)
        aq[dk] = *(const bf16x8*)(Qb +
            (size_t)(q0w + l32) * 64 + dk * 16 + hi * 8);

    f32x16 co0 = {}, co1 = {};   // ctx: rows=q (C layout), cols=d (dt*32+l32)

    // ---- prologue: stage tile 0 (4 glds/wave) + mask (2 glds/wave) ----
    glds16(Kb + (size_t)sr * 64 + sc,            &Ks[0][rb * 64]);
    glds16(Kb + (size_t)(sr + 8) * 64 + sc,      &Ks[0][(rb + 8) * 64]);
    glds16(Vb + (size_t)sr * 2048 + sc,          &Vs[0][rb * 64]);
    glds16(Vb + (size_t)(sr + 8) * 2048 + sc,    &Vs[0][(rb + 8) * 64]);
    // mask: 8KB = 8 glds of 1KB; wave w does chunks 2w, 2w+1.
    glds16((const __bf16*)mb + (size_t)(wave * 2) * 512 + lane * 8,
           (__bf16*)Ms + (wave * 2) * 512);
    glds16((const __bf16*)mb + (size_t)(wave * 2 + 1) * 512 + lane * 8,
           (__bf16*)Ms + (wave * 2 + 1) * 512);
    WAITCNT_VM0();
    BARRIER();

    for (int t = 0; t < 32; ++t) {
        const int kn = ((t + 1) & 31) * 64;   // wrap: final restage benign
        const int nb = (t + 1) & 1;
        const int cb = t & 1;
        // ---- stage next 64-key tile (4 glds/wave) ----
        glds16(Kb + (size_t)(kn + sr) * 64 + sc,         &Ks[nb][rb * 64]);
        glds16(Kb + (size_t)(kn + sr + 8) * 64 + sc,     &Ks[nb][(rb + 8) * 64]);
        glds16(Vb + (size_t)sr * 2048 + kn + sc,         &Vs[nb][rb * 64]);
        glds16(Vb + (size_t)(sr + 8) * 2048 + kn + sc,   &Vs[nb][(rb + 8) * 64]);

        const __bf16* Kt = &Ks[cb][0];
        const __bf16* Vtl = &Vs[cb][0];
        const int k0 = t * 64;

        // ---- phase 1: S^T = K Q^T, two 32-key groups, K=16 chain ----
        f32x16 st0 = {}, st1 = {};
        SETPRIO(1);
        #pragma unroll
        for (int dk = 0; dk < 4; ++dk) {
            const int g = dk * 2 + hi;             // global d-chunk
            const int c0 = (g ^ (l32 & 7)) * 8;    // swizzled (row&7 dep)
            bf16x8 ak0 = *(const bf16x8*)&Kt[l32 * 64 + c0];
            bf16x8 ak1 = *(const bf16x8*)&Kt[(32 + l32) * 64 + c0];
            st0 = MFMA32(ak0, aq[dk], st0);
            st1 = MFMA32(ak1, aq[dk], st1);
        }
        SETPRIO(0);

        // ---- phase 2+3 per 32-key group ----
        #pragma unroll
        for (int kg = 0; kg < 2; ++kg) {
            const f32x16 s = kg ? st1 : st0;
            const f32x4 zero4 = {};
            unsigned W[4][2];
            #pragma unroll
            for (int G = 0; G < 4; ++G) {
                f32x4 v;
                v[0] = s[G * 4 + 0]; v[1] = s[G * 4 + 1];
                v[2] = s[G * 4 + 2]; v[3] = s[G * 4 + 3];
                f32x4 mk = *(const f32x4*)&Ms[k0 + kg * 32 + G * 8 + hi * 4];
                v = v * 0.125f + mk;                      // v_pk_fma_f32
                v = __builtin_elementwise_max(v, zero4);  // v_pk_max_f32
                v = v * v;                                // v_pk_mul_f32
                bf16x2 w0, w1;
                w0[0] = (__bf16)v[0]; w0[1] = (__bf16)v[1];
                w1[0] = (__bf16)v[2]; w1[1] = (__bf16)v[3];
                W[G][0] = __builtin_bit_cast(unsigned, w0);
                W[G][1] = __builtin_bit_cast(unsigned, w1);
            }
            // repack to K=16 A-frags: lane l<->l+32 word exchange.
            u32x2 s00 = __builtin_amdgcn_permlane32_swap(W[0][0], W[1][0], false, false);
            u32x2 s01 = __builtin_amdgcn_permlane32_swap(W[0][1], W[1][1], false, false);
            u32x2 s10 = __builtin_amdgcn_permlane32_swap(W[2][0], W[3][0], false, false);
            u32x2 s11 = __builtin_amdgcn_permlane32_swap(W[2][1], W[3][1], false, false);
            u32x4 f0, f1;
            f0[0] = s00[0]; f0[1] = s01[0]; f0[2] = s00[1]; f0[3] = s01[1];
            f1[0] = s10[0]; f1[1] = s11[0]; f1[2] = s10[1]; f1[3] = s11[1];
            bf16x8 pa0 = __builtin_bit_cast(bf16x8, f0);   // keys kg*32+ 0..15
            bf16x8 pa1 = __builtin_bit_cast(bf16x8, f1);   // keys kg*32+16..31

            // ---- PV: co[dt] += P V, B = V^T slice from LDS ----
            SETPRIO(1);
            #pragma unroll
            for (int dt = 0; dt < 2; ++dt) {
                const int d = dt * 32 + l32;
                const int ch0 = (kg * 4 + hi) ^ (d & 7);
                const int ch1 = (kg * 4 + 2 + hi) ^ (d & 7);
                bf16x8 vb0 = *(const bf16x8*)&Vtl[d * 64 + ch0 * 8];
                bf16x8 vb1 = *(const bf16x8*)&Vtl[d * 64 + ch1 * 8];
                if (dt == 0) {
                    co0 = MFMA32(pa0, vb0, co0);
                    co0 = MFMA32(pa1, vb1, co0);
                } else {
                    co1 = MFMA32(pa0, vb0, co1);
                    co1 = MFMA32(pa1, vb1, co1);
                }
            }
            SETPRIO(0);
        }

        WAITCNT_VM0();          // this iter's stage (issued a full tile ago)
        BARRIER();              // buf nb fully written before anyone reads it
    }

    // Epilogue: q = q0w + (r&3)+8*(r>>2)+4*hi, d = dt*32 + l32.
    #pragma unroll
    for (int r = 0; r < 16; ++r) {
        int q = q0w + (r & 3) + 8 * (r >> 2) + 4 * hi;
        float* orow = &out[(((size_t)b * 2048 + q) * 16 + h) * 64];
        orow[l32]      = co0[r];
        orow[32 + l32] = co1[r];
    }
}

// ---------------------------------------------------------------------------
extern "C" void kernel_launch(void* const* d_in, const int* in_sizes, int n_in,
                              void* d_out, int out_size, void* d_ws, size_t ws_size,
                              hipStream_t stream) {
    const float* hidden = (const float*)d_in[0];   // [4,2048,1024]
    const float* mask   = (const float*)d_in[1];   // [4,1,1,2048]
    const float* Wq     = (const float*)d_in[2];
    const float* bq     = (const float*)d_in[3];
    const float* Wk     = (const float*)d_in[4];
    const float* bk     = (const float*)d_in[5];
    const float* Wv     = (const float*)d_in[6];
    const float* bv     = (const float*)d_in[7];
    float* out = (float*)d_out;

    __bf16* qws = (__bf16*)d_ws;                       // [64][2048][64]
    __bf16* kws = qws + (size_t)64 * 2048 * 64;        // [64][2048][64]
    __bf16* vws = kws + (size_t)64 * 2048 * 64;        // [64][64][2048]
    __bf16* Xb  = vws + (size_t)64 * 2048 * 64;        // [8192][1024]
    __bf16* Wqb = Xb  + (size_t)8192 * 1024;
    __bf16* Wkb = Wqb + (size_t)1024 * 1024;
    __bf16* Wvb = Wkb + (size_t)1024 * 1024;

    convert_kernel<<<dim3(5632), dim3(256), 0, stream>>>(hidden, Wq, Wk, Wv,
                                                         Xb, Wqb, Wkb, Wvb);
    qkv_gemm_kernel<<<dim3(24, 64), dim3(256), 0, stream>>>(Xb, Wqb, Wkb, Wvb,
                                                            bq, bk, bv,
                                                            qws, kws, vws);
    attn_kernel<<<dim3(64, 16), dim3(256), 0, stream>>>(qws, kws, vws, mask, out);
}